// Round 17
// baseline (1863.767 us; speedup 1.0000x reference)
//
#include <hip/hip_runtime.h>
#include <cstdint>

#define B_   128
#define T_   30
#define F_   2048
#define E_   512
#define H_   512
#define A_   512
#define CD_  128
#define CV_  64
#define V_   10000
#define VP_  10112
#define NN_  49
#define G4_  2048
#define LCAP_ 31

typedef __attribute__((ext_vector_type(4))) float f32x4;
typedef _Float16 h2v __attribute__((ext_vector_type(2)));
typedef _Float16 h4v __attribute__((ext_vector_type(4)));
typedef _Float16 h8v __attribute__((ext_vector_type(8)));

__device__ __forceinline__ float fdot2f(h2v a, h2v b, float c) {
#if __has_builtin(__builtin_amdgcn_fdot2)
  return __builtin_amdgcn_fdot2(a, b, c, false);
#else
  return c + (float)a[0]*(float)b[0] + (float)a[1]*(float)b[1];
#endif
}
__device__ __forceinline__ float dot8(h8v x, h8v w, float acc) {
  acc = fdot2f((h2v){x[0],x[1]}, (h2v){w[0],w[1]}, acc);
  acc = fdot2f((h2v){x[2],x[3]}, (h2v){w[2],w[3]}, acc);
  acc = fdot2f((h2v){x[4],x[5]}, (h2v){w[4],w[5]}, acc);
  acc = fdot2f((h2v){x[6],x[7]}, (h2v){w[6],w[7]}, acc);
  return acc;
}
__device__ __forceinline__ float tanh_f(float x) {
  x = fminf(fmaxf(x, -15.f), 15.f);
  float e = __expf(2.f * x);
  return __fdividef(e - 1.f, e + 1.f);
}
__device__ __forceinline__ float sig_f(float x) {
  return __fdividef(1.f, 1.f + __expf(-x));
}
// int8 decode helpers: 4 weights per u32 (little-endian bytes = k, k+1, k+2, k+3)
__device__ __forceinline__ void d4(uint wa, uint wb, float f0, float f1,
                                   float f2, float f3, float& a0, float& a1) {
  a0 = fmaf((float)((int)(wa << 24) >> 24), f0, a0);
  a0 = fmaf((float)((int)(wa << 16) >> 24), f1, a0);
  a0 = fmaf((float)((int)(wa <<  8) >> 24), f2, a0);
  a0 = fmaf((float)((int)wa >> 24),         f3, a0);
  a1 = fmaf((float)((int)(wb << 24) >> 24), f0, a1);
  a1 = fmaf((float)((int)(wb << 16) >> 24), f1, a1);
  a1 = fmaf((float)((int)(wb <<  8) >> 24), f2, a1);
  a1 = fmaf((float)((int)wb >> 24),         f3, a1);
}
__device__ __forceinline__ void d4s(uint w, float f0, float f1,
                                    float f2, float f3, float& a) {
  a = fmaf((float)((int)(w << 24) >> 24), f0, a);
  a = fmaf((float)((int)(w << 16) >> 24), f1, a);
  a = fmaf((float)((int)(w <<  8) >> 24), f2, a);
  a = fmaf((float)((int)w >> 24),         f3, a);
}

// ================= fp16 MFMA GEMM: C = A(M,K) @ B(N,K)^T (+bias) =================
template<int OUT_H, int BIAS>
__global__ __launch_bounds__(256)
void gemm_h16(const _Float16* __restrict__ A, int lda,
              const _Float16* __restrict__ B, int ldb,
              const float* __restrict__ bias,
              void* __restrict__ Cv, int ldc, int Nreal, int K) {
  __shared__ _Float16 As[128 * 32];
  __shared__ _Float16 Bs[128 * 32];
  const int tid = threadIdx.x;
  const int m0 = blockIdx.y * 128, n0 = blockIdx.x * 128;
  const int lane = tid & 63, wid = tid >> 6;
  const int wm = (wid >> 1) * 64, wn = (wid & 1) * 64;
  f32x4 acc[4][4] = {};
  const int lr = tid >> 2;
  const int lc = (tid & 3) * 8;
  const _Float16* Ag  = A + (size_t)(m0 + lr) * lda + lc;
  const _Float16* Ag2 = Ag + (size_t)64 * lda;
  const _Float16* Bg  = B + (size_t)(n0 + lr) * ldb + lc;
  const _Float16* Bg2 = Bg + (size_t)64 * ldb;
  auto* lAs = (__attribute__((address_space(3))) char*)As;
  auto* lBs = (__attribute__((address_space(3))) char*)Bs;
  const int ldst = lr * 64 + (tid & 3) * 16;
  const int ar = wm + (lane & 15);
  const int br = wn + (lane & 15);
  const int kc = (lane >> 4) * 8;
  for (int k0 = 0; k0 < K; k0 += 32) {
    __builtin_amdgcn_global_load_lds((const __attribute__((address_space(1))) char*)(Ag  + k0), lAs + ldst,        16, 0, 0);
    __builtin_amdgcn_global_load_lds((const __attribute__((address_space(1))) char*)(Ag2 + k0), lAs + 4096 + ldst, 16, 0, 0);
    __builtin_amdgcn_global_load_lds((const __attribute__((address_space(1))) char*)(Bg  + k0), lBs + ldst,        16, 0, 0);
    __builtin_amdgcn_global_load_lds((const __attribute__((address_space(1))) char*)(Bg2 + k0), lBs + 4096 + ldst, 16, 0, 0);
    __syncthreads();
    h8v af[4], bfr[4];
#pragma unroll
    for (int i = 0; i < 4; ++i) {
      af[i]  = *(const h8v*)&As[(ar + i * 16) * 32 + kc];
      bfr[i] = *(const h8v*)&Bs[(br + i * 16) * 32 + kc];
    }
#pragma unroll
    for (int i = 0; i < 4; ++i)
#pragma unroll
      for (int j = 0; j < 4; ++j)
        acc[i][j] = __builtin_amdgcn_mfma_f32_16x16x32_f16(af[i], bfr[j], acc[i][j], 0, 0, 0);
    __syncthreads();
  }
  const int orow = m0 + wm + (lane >> 4) * 4;
  const int ocol = n0 + wn + (lane & 15);
#pragma unroll
  for (int j = 0; j < 4; ++j) {
    const int col = ocol + j * 16;
    if (col >= Nreal) continue;
    const float bv = BIAS ? bias[col] : 0.f;
#pragma unroll
    for (int i = 0; i < 4; ++i) {
#pragma unroll
      for (int r = 0; r < 4; ++r) {
        const int row = orow + i * 16 + r;
        const float v = acc[i][j][r] + bv;
        if (OUT_H) ((_Float16*)Cv)[(size_t)row * ldc + col] = (_Float16)v;
        else       ((float*)Cv)[(size_t)row * ldc + col] = v;
      }
    }
  }
}

// ---------------- att_feats (B,F,49) -> att_th (B,49,F) fp16 ----------------
__global__ __launch_bounds__(256)
void transpose_att(const float* __restrict__ af, _Float16* __restrict__ att_th) {
  __shared__ float s[64 * NN_];
  const int b = blockIdx.y, f0 = blockIdx.x * 64;
  const float* src = af + (size_t)b * F_ * NN_ + (size_t)f0 * NN_;
  for (int i = threadIdx.x; i < 64 * NN_; i += 256) s[i] = src[i];
  __syncthreads();
  _Float16* dst = att_th + (size_t)b * NN_ * F_ + f0;
  for (int i = threadIdx.x; i < NN_ * 64; i += 256) {
    int n = i >> 6, j = i & 63;
    dst[(size_t)n * F_ + j] = (_Float16)s[j * NN_ + n];
  }
}

// ---------------- fp32 (strided cols) -> packed fp16, row pad ----------------
__global__ void pack_h16(const float* __restrict__ src, int src_ld, int c0,
                         _Float16* __restrict__ dst, int C, int R, int Rpad) {
  int i = blockIdx.x * 256 + threadIdx.x;
  if (i >= Rpad * C) return;
  int r = i / C, c = i - r * C;
  float v = (r < R) ? src[(size_t)r * src_ld + c0 + c] : 0.f;
  dst[i] = (_Float16)v;
}

// ---------------- fp32 -> fp16 k-interleaved: dst[(k/8)*R*8 + r*8 + k%8] ----------------
__global__ void pack_ki8(const float* __restrict__ src, int src_ld, int c0,
                         _Float16* __restrict__ dst, int R, int K) {
  int i = blockIdx.x * 256 + threadIdx.x;
  if (i >= R * K) return;
  int k7 = i & 7;
  int t = i >> 3;
  int r = t & (R - 1);      // R power of two
  int kb = t / R;
  int k = kb * 8 + k7;
  dst[i] = (_Float16)src[(size_t)r * src_ld + c0 + k];
}

// ---------------- fp32 rows -> int8 (per-row scale), k16-interleaved ----------------
// dst byte addr = ((k/16)*R + r)*16 + (k%16); scale[r] = absmax/127
__global__ __launch_bounds__(64)
void quant_rows(const float* __restrict__ src, int ld, int R, int K,
                int8_t* __restrict__ dst, float* __restrict__ scale) {
  const int r = blockIdx.x, lane = threadIdx.x;
  const float* row = src + (size_t)r * ld;
  float m = 0.f;
  for (int j = lane; j < K; j += 64) m = fmaxf(m, fabsf(row[j]));
#pragma unroll
  for (int off = 32; off > 0; off >>= 1) m = fmaxf(m, __shfl_xor(m, off));
  const float inv = (m > 0.f) ? 127.f / m : 0.f;
  if (lane == 0) scale[r] = m / 127.f;
  for (int j = lane; j < K; j += 64) {
    int q = (int)rintf(row[j] * inv);
    q = max(-127, min(127, q));
    dst[((size_t)(j >> 4) * R + r) * 16 + (j & 15)] = (int8_t)q;
  }
}

// ---------------- count-embed MLP (fp32) ----------------
__global__ __launch_bounds__(128)
void count_embed_k(const float* __restrict__ cv, const float* __restrict__ w1,
                   const float* __restrict__ b1, const float* __restrict__ w2,
                   const float* __restrict__ b2, float* __restrict__ ce) {
  const int b = blockIdx.x, tid = threadIdx.x;
  __shared__ float s_cv[CV_], s_h[CD_];
  if (tid < CV_) s_cv[tid] = cv[b * CV_ + tid];
  __syncthreads();
  float acc = b1[tid];
  for (int k = 0; k < CV_; ++k) acc += s_cv[k] * w1[tid * CV_ + k];
  s_h[tid] = fmaxf(acc, 0.f);
  __syncthreads();
  float acc2 = b2[tid];
  for (int k = 0; k < CD_; ++k) acc2 += s_h[k] * w2[tid * CD_ + k];
  ce[b * CD_ + tid] = acc2;
}

// ---------------- gather word embeddings -> fp16 (B*T, E) ----------------
__global__ __launch_bounds__(128)
void gather_we(const int* __restrict__ captions, const float* __restrict__ embed_w,
               _Float16* __restrict__ we_h) {
  const int r = blockIdx.x;
  const int b = r / T_, t = r - b * T_;
  const int idx = captions[b * LCAP_ + t];
  const float4 v = ((const float4*)(embed_w + (size_t)idx * E_))[threadIdx.x];
  h4v o = { (_Float16)v.x, (_Float16)v.y, (_Float16)v.z, (_Float16)v.w };
  ((h4v*)(we_h + (size_t)r * E_))[threadIdx.x] = o;
}

// ================= persistent per-batch sequential loop =================
// Round-16 verified structure; whh/atthw streams now int8 (per-row scaled),
// halving per-step stream loads (the latency-bound bottleneck). Decode is
// wave-local VALU (sext+cvt+fma), scales applied once per accumulator.
__global__ __launch_bounds__(1024)
void seq_loop(const _Float16* __restrict__ fcfeat_h,   // B x F
              const _Float16* __restrict__ fcproj_k,   // ki8 R=512 K=F
              const float* __restrict__ fcproj_b,
              const _Float16* __restrict__ wcnt_h,     // 2048 x CD
              const float* __restrict__ ce,            // B x CD f32
              const float* __restrict__ b_ih, const float* __restrict__ b_hh,
              const int8_t* __restrict__ atthwq,       // int8 k16 R=512 K=512
              const float* __restrict__ sAtt,          // [512]
              const float* __restrict__ att_hb,
              const _Float16* __restrict__ attproj_h,  // B x 49 x 512
              const float* __restrict__ alpha_w, const float* __restrict__ alpha_b,
              const _Float16* __restrict__ attW_h,     // B x 49 x 2048
              const float* __restrict__ we_proj,       // (B*T) x 2048 f32
              const int8_t* __restrict__ whhq,         // int8 k16 R=2048 K=512
              const float* __restrict__ sWhh,          // [2048]
              _Float16* __restrict__ H_all_h,          // (B*T) x 512
              float* __restrict__ out_alpha) {         // B x T x 49
  const int b = blockIdx.x, tid = threadIdx.x;
  __shared__ _Float16 s_ap[NN_ * A_];      // 50 KB: attproj[b] (+att_fb)
  __shared__ _Float16 s_h[H_];             // 1 KB
  __shared__ float    s_hp2[2][A_];        // 4 KB
  __shared__ _Float16 s_gates[G4_];        // 4 KB (prologue: fcfeat)
  __shared__ float    s_sc[64];
  __shared__ float    s_alpha[64];
  __shared__ float    s_ce[CD_];

  const int a9 = tid & 511, half = tid >> 9;
  const int wv = tid >> 6, lane = tid & 63;

  // ---- prologue: fill LDS ----
  ((uint*)s_gates)[tid] = ((const uint*)(fcfeat_h + (size_t)b * F_))[tid];
  {
    const uint* src = (const uint*)(attproj_h + (size_t)b * NN_ * A_);
    for (int i = tid; i < NN_ * A_ / 2; i += 1024) ((uint*)s_ap)[i] = src[i];
  }
  if (tid < CD_) s_ce[tid] = ce[b * CD_ + tid];
  h2v aW[NN_];
  {
    const _Float16* base = attW_h + (size_t)b * NN_ * G4_ + 2 * tid;
#pragma unroll
    for (int n = 0; n < NN_; ++n) aW[n] = *(const h2v*)(base + (size_t)n * G4_);
  }
  float aw8[8];
#pragma unroll
  for (int i = 0; i < 8; ++i) aw8[i] = alpha_w[lane * 8 + i];
  const float ab  = alpha_b[0];
  const float ahb = (half == 0) ? att_hb[a9] : 0.f;
  const float sA  = sAtt[a9];
  const float s0  = sWhh[2 * tid];
  const float s1  = sWhh[2 * tid + 1];
  __syncthreads();

  // h0 (threads 0..511): tanh(fcfeat . fcproj + b)
  float c_state = 0.f;
  if (tid < H_) {
    float acc = fcproj_b[tid];
    const h8v* xv = (const h8v*)s_gates;
    const h8v* wp = (const h8v*)fcproj_k;
    for (int k8 = 0; k8 < F_ / 8; ++k8)
      acc = dot8(xv[k8], wp[(size_t)k8 * 512 + tid], acc);
    s_h[tid] = (_Float16)tanh_f(acc);
  }
  // base for gate pair p = {2tid, 2tid+1}
  float base0 = b_ih[2 * tid]     + b_hh[2 * tid];
  float base1 = b_ih[2 * tid + 1] + b_hh[2 * tid + 1];
  {
    const h8v* w0 = (const h8v*)(wcnt_h + (size_t)(2 * tid) * CD_);
    const h8v* w1 = (const h8v*)(wcnt_h + (size_t)(2 * tid + 1) * CD_);
#pragma unroll
    for (int k8 = 0; k8 < CD_ / 8; ++k8) {
      const h8v a = w0[k8], c = w1[k8];
#pragma unroll
      for (int i = 0; i < 8; ++i) {
        const float cv = s_ce[k8 * 8 + i];
        base0 += cv * (float)a[i];
        base1 += cv * (float)c[i];
      }
    }
  }
  __syncthreads();

  const h8v* hv = (const h8v*)s_h;

  for (int t = 0; t < T_; ++t) {
    // ---- A: hp[a9] partial (k16 chunks, int8 weights) ----
    {
      float accq = 0.f;
#pragma unroll 4
      for (int ci = 0; ci < 16; ++ci) {
        const int c = half * 16 + ci;
        const uint4 u = *(const uint4*)(atthwq + ((size_t)c * 512 + a9) * 16);
        const h8v x0 = hv[2 * c], x1 = hv[2 * c + 1];
        d4s(u.x, (float)x0[0], (float)x0[1], (float)x0[2], (float)x0[3], accq);
        d4s(u.y, (float)x0[4], (float)x0[5], (float)x0[6], (float)x0[7], accq);
        d4s(u.z, (float)x1[0], (float)x1[1], (float)x1[2], (float)x1[3], accq);
        d4s(u.w, (float)x1[4], (float)x1[5], (float)x1[6], (float)x1[7], accq);
      }
      s_hp2[half][a9] = ahb + accq * sA;
    }
    __syncthreads();
    // ---- B: scores[n] = sum_a tanh(attproj[n][a] + hp[a]) * aw[a] ----
    {
      float hp8[8];
#pragma unroll
      for (int i = 0; i < 8; ++i) {
        const int a = lane * 8 + i;
        hp8[i] = s_hp2[0][a] + s_hp2[1][a];
      }
      const int Q = (wv == 0) ? 4 : 3;
      for (int q = 0; q < Q; ++q) {
        const int n = wv + 16 * q;
        const h8v apv = *(const h8v*)&s_ap[n * A_ + lane * 8];
        float s = 0.f;
#pragma unroll
        for (int i = 0; i < 8; ++i) {
          const float x = (float)apv[i] + hp8[i];
          const float e = __expf(2.f * fminf(fmaxf(x, -15.f), 15.f));
          s += __fdividef(e - 1.f, e + 1.f) * aw8[i];
        }
#pragma unroll
        for (int off = 32; off > 0; off >>= 1) s += __shfl_xor(s, off);
        if (lane == 0) s_sc[n] = s + ab;
      }
    }
    __syncthreads();
    // ---- C: softmax over 49 (wave 0) ----
    if (wv == 0) {
      float v = (lane < NN_) ? s_sc[lane] : -3.0e38f;
      float m = v;
#pragma unroll
      for (int off = 32; off > 0; off >>= 1) m = fmaxf(m, __shfl_xor(m, off));
      float e = (lane < NN_) ? __expf(v - m) : 0.f;
      float ssum = e;
#pragma unroll
      for (int off = 32; off > 0; off >>= 1) ssum += __shfl_xor(ssum, off);
      const float a = __fdividef(e, ssum);
      if (lane < NN_) {
        s_alpha[lane] = a;
        out_alpha[((size_t)b * T_ + t) * NN_ + lane] = a;
      }
    }
    __syncthreads();
    // ---- D: gates p={2tid,2tid+1} = base + we_proj + alpha@attW(reg) + h@whh(int8) ----
    {
      const float2 wp = *(const float2*)(we_proj + ((size_t)b * T_ + t) * G4_ + 2 * tid);
      float acc0 = base0 + wp.x, acc1 = base1 + wp.y;
#pragma unroll
      for (int n = 0; n < NN_; ++n) {
        const float al = s_alpha[n];
        acc0 += al * (float)aW[n][0];
        acc1 += al * (float)aW[n][1];
      }
      float aq0 = 0.f, aq1 = 0.f;
#pragma unroll 2
      for (int c = 0; c < 32; ++c) {
        const uint4 qa = *(const uint4*)(whhq + ((size_t)c * G4_ + 2 * tid) * 16);
        const uint4 qb = *(const uint4*)(whhq + ((size_t)c * G4_ + 2 * tid + 1) * 16);
        const h8v x0 = hv[2 * c], x1 = hv[2 * c + 1];
        d4(qa.x, qb.x, (float)x0[0], (float)x0[1], (float)x0[2], (float)x0[3], aq0, aq1);
        d4(qa.y, qb.y, (float)x0[4], (float)x0[5], (float)x0[6], (float)x0[7], aq0, aq1);
        d4(qa.z, qb.z, (float)x1[0], (float)x1[1], (float)x1[2], (float)x1[3], aq0, aq1);
        d4(qa.w, qb.w, (float)x1[4], (float)x1[5], (float)x1[6], (float)x1[7], aq0, aq1);
      }
      acc0 += aq0 * s0;
      acc1 += aq1 * s1;
      *(h2v*)&s_gates[2 * tid] = (h2v){ (_Float16)acc0, (_Float16)acc1 };
    }
    __syncthreads();
    // ---- E: LSTM cell (threads 0..511) ----
    if (tid < H_) {
      const int j = tid;
      const float gi = (float)s_gates[j];
      const float gf = (float)s_gates[512 + j];
      const float gg = (float)s_gates[1024 + j];
      const float go = (float)s_gates[1536 + j];
      const float si = sig_f(gi), sf = sig_f(gf), so = sig_f(go);
      c_state = sf * c_state + si * tanh_f(gg);
      const float hn = so * tanh_f(c_state);
      s_h[j] = (_Float16)hn;
      H_all_h[((size_t)b * T_ + t) * H_ + j] = (_Float16)hn;
    }
    __syncthreads();
  }
}

extern "C" void kernel_launch(void* const* d_in, const int* in_sizes, int n_in,
                              void* d_out, int out_size, void* d_ws, size_t ws_size,
                              hipStream_t stream) {
  const float* att_feats  = (const float*)d_in[0];
  const float* fc_feats   = (const float*)d_in[1];
  const int*   captions   = (const int*)  d_in[2];
  const float* count_vecs = (const float*)d_in[3];
  const float* embed_w    = (const float*)d_in[4];
  const float* cm_w1      = (const float*)d_in[5];
  const float* cm_b1      = (const float*)d_in[6];
  const float* cm_w2      = (const float*)d_in[7];
  const float* cm_b2      = (const float*)d_in[8];
  const float* att_hw     = (const float*)d_in[9];
  const float* att_hb     = (const float*)d_in[10];
  const float* att_fw     = (const float*)d_in[11];
  const float* att_fb     = (const float*)d_in[12];
  const float* alpha_w    = (const float*)d_in[13];
  const float* alpha_b    = (const float*)d_in[14];
  const float* fcproj_w   = (const float*)d_in[15];
  const float* fcproj_b   = (const float*)d_in[16];
  const float* w_ih       = (const float*)d_in[17];
  const float* b_ih       = (const float*)d_in[18];
  const float* w_hh       = (const float*)d_in[19];
  const float* b_hh       = (const float*)d_in[20];
  const float* fc_w       = (const float*)d_in[21];
  const float* fc_b       = (const float*)d_in[22];
  float* out = (float*)d_out;

  char* wsb = (char*)d_ws;
  size_t off = 0;
  auto nxt = [&](size_t bytes) { char* p = wsb + off; off += (bytes + 255) & ~(size_t)255; return p; };
  _Float16* att_th    = (_Float16*)nxt((size_t)B_*NN_*F_*2);
  _Float16* attW_h    = (_Float16*)nxt((size_t)B_*NN_*G4_*2);
  _Float16* attproj_h = (_Float16*)nxt((size_t)B_*NN_*A_*2);
  _Float16* we_h      = (_Float16*)nxt((size_t)B_*T_*E_*2);
  _Float16* H_all_h   = (_Float16*)nxt((size_t)B_*T_*H_*2);
  _Float16* w_ihF_h   = (_Float16*)nxt((size_t)G4_*F_*2);
  _Float16* w_ih0_h   = (_Float16*)nxt((size_t)G4_*E_*2);
  _Float16* wcnt_h    = (_Float16*)nxt((size_t)G4_*CD_*2);
  _Float16* fc_w_h    = (_Float16*)nxt((size_t)VP_*H_*2);
  _Float16* att_fw_h  = (_Float16*)nxt((size_t)A_*F_*2);
  _Float16* fcfeat_h  = (_Float16*)nxt((size_t)B_*F_*2);
  _Float16* fcproj_k  = (_Float16*)nxt((size_t)H_*F_*2);
  int8_t*   whhq      = (int8_t*)nxt((size_t)G4_*H_);
  int8_t*   atthwq    = (int8_t*)nxt((size_t)A_*H_);
  float*    sWhh      = (float*)nxt((size_t)G4_*4);
  float*    sAtt      = (float*)nxt((size_t)A_*4);
  float*    we_proj   = (float*)nxt((size_t)B_*T_*G4_*4);
  float*    ce        = (float*)nxt((size_t)B_*CD_*4);
  if (off > ws_size) return;

  const size_t ALPHA_OFF = (size_t)B_ * T_ * V_;

  // ---- packs & small precompute ----
  transpose_att<<<dim3(F_/64, B_), 256, 0, stream>>>(att_feats, att_th);
  pack_h16<<<((size_t)B_*F_ + 255)/256, 256, 0, stream>>>(fc_feats, F_, 0, fcfeat_h, F_, B_, B_);
  pack_h16<<<((size_t)G4_*F_ + 255)/256, 256, 0, stream>>>(w_ih, E_+F_+CD_, E_, w_ihF_h, F_, G4_, G4_);
  pack_h16<<<((size_t)G4_*E_ + 255)/256, 256, 0, stream>>>(w_ih, E_+F_+CD_, 0, w_ih0_h, E_, G4_, G4_);
  pack_h16<<<((size_t)G4_*CD_ + 255)/256, 256, 0, stream>>>(w_ih, E_+F_+CD_, E_+F_, wcnt_h, CD_, G4_, G4_);
  pack_h16<<<((size_t)A_*F_ + 255)/256, 256, 0, stream>>>(att_fw, F_, 0, att_fw_h, F_, A_, A_);
  pack_h16<<<((size_t)VP_*H_ + 255)/256, 256, 0, stream>>>(fc_w, H_, 0, fc_w_h, H_, V_, VP_);
  pack_ki8<<<((size_t)H_*F_ + 255)/256, 256, 0, stream>>>(fcproj_w, F_, 0, fcproj_k, H_, F_);
  quant_rows<<<G4_, 64, 0, stream>>>(w_hh, H_, G4_, H_, whhq, sWhh);
  quant_rows<<<A_, 64, 0, stream>>>(att_hw, H_, A_, H_, atthwq, sAtt);
  count_embed_k<<<B_, 128, 0, stream>>>(count_vecs, cm_w1, cm_b1, cm_w2, cm_b2, ce);
  gather_we<<<B_ * T_, 128, 0, stream>>>(captions, embed_w, we_h);

  // ---- MFMA precompute GEMMs ----
  gemm_h16<1,1><<<dim3(A_/128, (B_*NN_)/128), 256, 0, stream>>>(
      att_th, F_, att_fw_h, F_, att_fb, attproj_h, A_, A_, F_);
  gemm_h16<1,0><<<dim3(G4_/128, (B_*NN_)/128), 256, 0, stream>>>(
      att_th, F_, w_ihF_h, F_, nullptr, attW_h, G4_, G4_, F_);
  gemm_h16<0,0><<<dim3(G4_/128, (B_*T_)/128), 256, 0, stream>>>(
      we_h, E_, w_ih0_h, E_, nullptr, we_proj, G4_, G4_, E_);

  // ---- persistent sequential loop ----
  seq_loop<<<B_, 1024, 0, stream>>>(fcfeat_h, fcproj_k, fcproj_b,
                                    wcnt_h, ce, b_ih, b_hh,
                                    atthwq, sAtt, att_hb,
                                    attproj_h, alpha_w, alpha_b,
                                    attW_h, we_proj, whhq, sWhh,
                                    H_all_h, out + ALPHA_OFF);

  // ---- logits = H_all @ fc_w^T + fc_b -> out (B*T, V) ----
  gemm_h16<0,1><<<dim3(VP_/128, (B_*T_)/128), 256, 0, stream>>>(
      H_all_h, H_, fc_w_h, H_, fc_b, out, V_, V_, H_);
}

// Round 18
// 1838.527 us; speedup vs baseline: 1.0137x; 1.0137x over previous
//
#include <hip/hip_runtime.h>
#include <cstdint>

#define B_   128
#define T_   30
#define F_   2048
#define E_   512
#define H_   512
#define A_   512
#define CD_  128
#define CV_  64
#define V_   10000
#define VP_  10112
#define NN_  49
#define G4_  2048
#define LCAP_ 31

typedef __attribute__((ext_vector_type(4))) float f32x4;
typedef _Float16 h2v __attribute__((ext_vector_type(2)));
typedef _Float16 h4v __attribute__((ext_vector_type(4)));
typedef _Float16 h8v __attribute__((ext_vector_type(8)));

__device__ __forceinline__ float fdot2f(h2v a, h2v b, float c) {
#if __has_builtin(__builtin_amdgcn_fdot2)
  return __builtin_amdgcn_fdot2(a, b, c, false);
#else
  return c + (float)a[0]*(float)b[0] + (float)a[1]*(float)b[1];
#endif
}
__device__ __forceinline__ float dot8(h8v x, h8v w, float acc) {
  acc = fdot2f((h2v){x[0],x[1]}, (h2v){w[0],w[1]}, acc);
  acc = fdot2f((h2v){x[2],x[3]}, (h2v){w[2],w[3]}, acc);
  acc = fdot2f((h2v){x[4],x[5]}, (h2v){w[4],w[5]}, acc);
  acc = fdot2f((h2v){x[6],x[7]}, (h2v){w[6],w[7]}, acc);
  return acc;
}
__device__ __forceinline__ float tanh_f(float x) {
  x = fminf(fmaxf(x, -15.f), 15.f);
  float e = __expf(2.f * x);
  return __fdividef(e - 1.f, e + 1.f);
}
__device__ __forceinline__ float sig_f(float x) {
  return __fdividef(1.f, 1.f + __expf(-x));
}

// ================= fp16 MFMA GEMM: C = A(M,K) @ B(N,K)^T (+bias) =================
template<int OUT_H, int BIAS>
__global__ __launch_bounds__(256)
void gemm_h16(const _Float16* __restrict__ A, int lda,
              const _Float16* __restrict__ B, int ldb,
              const float* __restrict__ bias,
              void* __restrict__ Cv, int ldc, int Nreal, int K) {
  __shared__ _Float16 As[128 * 32];
  __shared__ _Float16 Bs[128 * 32];
  const int tid = threadIdx.x;
  const int m0 = blockIdx.y * 128, n0 = blockIdx.x * 128;
  const int lane = tid & 63, wid = tid >> 6;
  const int wm = (wid >> 1) * 64, wn = (wid & 1) * 64;
  f32x4 acc[4][4] = {};
  const int lr = tid >> 2;
  const int lc = (tid & 3) * 8;
  const _Float16* Ag  = A + (size_t)(m0 + lr) * lda + lc;
  const _Float16* Ag2 = Ag + (size_t)64 * lda;
  const _Float16* Bg  = B + (size_t)(n0 + lr) * ldb + lc;
  const _Float16* Bg2 = Bg + (size_t)64 * ldb;
  auto* lAs = (__attribute__((address_space(3))) char*)As;
  auto* lBs = (__attribute__((address_space(3))) char*)Bs;
  const int ldst = lr * 64 + (tid & 3) * 16;
  const int ar = wm + (lane & 15);
  const int br = wn + (lane & 15);
  const int kc = (lane >> 4) * 8;
  for (int k0 = 0; k0 < K; k0 += 32) {
    __builtin_amdgcn_global_load_lds((const __attribute__((address_space(1))) char*)(Ag  + k0), lAs + ldst,        16, 0, 0);
    __builtin_amdgcn_global_load_lds((const __attribute__((address_space(1))) char*)(Ag2 + k0), lAs + 4096 + ldst, 16, 0, 0);
    __builtin_amdgcn_global_load_lds((const __attribute__((address_space(1))) char*)(Bg  + k0), lBs + ldst,        16, 0, 0);
    __builtin_amdgcn_global_load_lds((const __attribute__((address_space(1))) char*)(Bg2 + k0), lBs + 4096 + ldst, 16, 0, 0);
    __syncthreads();
    h8v af[4], bfr[4];
#pragma unroll
    for (int i = 0; i < 4; ++i) {
      af[i]  = *(const h8v*)&As[(ar + i * 16) * 32 + kc];
      bfr[i] = *(const h8v*)&Bs[(br + i * 16) * 32 + kc];
    }
#pragma unroll
    for (int i = 0; i < 4; ++i)
#pragma unroll
      for (int j = 0; j < 4; ++j)
        acc[i][j] = __builtin_amdgcn_mfma_f32_16x16x32_f16(af[i], bfr[j], acc[i][j], 0, 0, 0);
    __syncthreads();
  }
  const int orow = m0 + wm + (lane >> 4) * 4;
  const int ocol = n0 + wn + (lane & 15);
#pragma unroll
  for (int j = 0; j < 4; ++j) {
    const int col = ocol + j * 16;
    if (col >= Nreal) continue;
    const float bv = BIAS ? bias[col] : 0.f;
#pragma unroll
    for (int i = 0; i < 4; ++i) {
#pragma unroll
      for (int r = 0; r < 4; ++r) {
        const int row = orow + i * 16 + r;
        const float v = acc[i][j][r] + bv;
        if (OUT_H) ((_Float16*)Cv)[(size_t)row * ldc + col] = (_Float16)v;
        else       ((float*)Cv)[(size_t)row * ldc + col] = v;
      }
    }
  }
}

// ---------------- att_feats (B,F,49) -> att_th (B,49,F) fp16 ----------------
__global__ __launch_bounds__(256)
void transpose_att(const float* __restrict__ af, _Float16* __restrict__ att_th) {
  __shared__ float s[64 * NN_];
  const int b = blockIdx.y, f0 = blockIdx.x * 64;
  const float* src = af + (size_t)b * F_ * NN_ + (size_t)f0 * NN_;
  for (int i = threadIdx.x; i < 64 * NN_; i += 256) s[i] = src[i];
  __syncthreads();
  _Float16* dst = att_th + (size_t)b * NN_ * F_ + f0;
  for (int i = threadIdx.x; i < NN_ * 64; i += 256) {
    int n = i >> 6, j = i & 63;
    dst[(size_t)n * F_ + j] = (_Float16)s[j * NN_ + n];
  }
}

// ---------------- fp32 (strided cols) -> packed fp16, row pad ----------------
__global__ void pack_h16(const float* __restrict__ src, int src_ld, int c0,
                         _Float16* __restrict__ dst, int C, int R, int Rpad) {
  int i = blockIdx.x * 256 + threadIdx.x;
  if (i >= Rpad * C) return;
  int r = i / C, c = i - r * C;
  float v = (r < R) ? src[(size_t)r * src_ld + c0 + c] : 0.f;
  dst[i] = (_Float16)v;
}

// ---------------- fp32 -> fp16 k-interleaved: dst[(k/8)*R*8 + r*8 + k%8] ----------------
__global__ void pack_ki8(const float* __restrict__ src, int src_ld, int c0,
                         _Float16* __restrict__ dst, int R, int K) {
  int i = blockIdx.x * 256 + threadIdx.x;
  if (i >= R * K) return;
  int k7 = i & 7;
  int t = i >> 3;
  int r = t & (R - 1);      // R power of two
  int kb = t / R;
  int k = kb * 8 + k7;
  dst[i] = (_Float16)src[(size_t)r * src_ld + c0 + k];
}

// ---------------- count-embed MLP (fp32) ----------------
__global__ __launch_bounds__(128)
void count_embed_k(const float* __restrict__ cv, const float* __restrict__ w1,
                   const float* __restrict__ b1, const float* __restrict__ w2,
                   const float* __restrict__ b2, float* __restrict__ ce) {
  const int b = blockIdx.x, tid = threadIdx.x;
  __shared__ float s_cv[CV_], s_h[CD_];
  if (tid < CV_) s_cv[tid] = cv[b * CV_ + tid];
  __syncthreads();
  float acc = b1[tid];
  for (int k = 0; k < CV_; ++k) acc += s_cv[k] * w1[tid * CV_ + k];
  s_h[tid] = fmaxf(acc, 0.f);
  __syncthreads();
  float acc2 = b2[tid];
  for (int k = 0; k < CD_; ++k) acc2 += s_h[k] * w2[tid * CD_ + k];
  ce[b * CD_ + tid] = acc2;
}

// ---------------- gather word embeddings -> fp16 (B*T, E) ----------------
__global__ __launch_bounds__(128)
void gather_we(const int* __restrict__ captions, const float* __restrict__ embed_w,
               _Float16* __restrict__ we_h) {
  const int r = blockIdx.x;
  const int b = r / T_, t = r - b * T_;
  const int idx = captions[b * LCAP_ + t];
  const float4 v = ((const float4*)(embed_w + (size_t)idx * E_))[threadIdx.x];
  h4v o = { (_Float16)v.x, (_Float16)v.y, (_Float16)v.z, (_Float16)v.w };
  ((h4v*)(we_h + (size_t)r * E_))[threadIdx.x] = o;
}

// ================= persistent per-batch sequential loop =================
// 128 blocks (one per b) x 1024 threads.
// attproj[b] lives in LDS (50KB, loaded once); attW[b] columns live in registers
// (each thread owns gate pair p = {2tid, 2tid+1}); whh/atthw stream from L2/L3.
// Session-verified best structure (rounds 4/12/13/16: 1838-1847 us, absmax 1.95e-3).
// Per-step time (~51 us) measured invariant to stream bytes (int8 test, r17),
// load count, and pipelining attempts -> latency-chain structural floor.
__global__ __launch_bounds__(1024)
void seq_loop(const _Float16* __restrict__ fcfeat_h,   // B x F
              const _Float16* __restrict__ fcproj_k,   // ki8 R=512 K=F
              const float* __restrict__ fcproj_b,
              const _Float16* __restrict__ wcnt_h,     // 2048 x CD
              const float* __restrict__ ce,            // B x CD f32
              const float* __restrict__ b_ih, const float* __restrict__ b_hh,
              const _Float16* __restrict__ atthw_k,    // ki8 R=512 K=512
              const float* __restrict__ att_hb,
              const _Float16* __restrict__ attproj_h,  // B x 49 x 512
              const float* __restrict__ alpha_w, const float* __restrict__ alpha_b,
              const _Float16* __restrict__ attW_h,     // B x 49 x 2048
              const float* __restrict__ we_proj,       // (B*T) x 2048 f32
              const _Float16* __restrict__ whh_k,      // ki8 R=2048 K=512
              _Float16* __restrict__ H_all_h,          // (B*T) x 512
              float* __restrict__ out_alpha) {         // B x T x 49
  const int b = blockIdx.x, tid = threadIdx.x;
  __shared__ _Float16 s_ap[NN_ * A_];      // 50 KB: attproj[b] (+att_fb)
  __shared__ _Float16 s_h[H_];             // 1 KB
  __shared__ float    s_hp2[2][A_];        // 4 KB
  __shared__ _Float16 s_gates[G4_];        // 4 KB (fp16 gate pre-acts; prologue: fcfeat)
  __shared__ float    s_sc[64];
  __shared__ float    s_alpha[64];
  __shared__ float    s_ce[CD_];

  const int a9 = tid & 511, half = tid >> 9;
  const int wv = tid >> 6, lane = tid & 63;

  // ---- prologue: fill LDS ----
  ((uint*)s_gates)[tid] = ((const uint*)(fcfeat_h + (size_t)b * F_))[tid];
  {
    const uint* src = (const uint*)(attproj_h + (size_t)b * NN_ * A_);
    for (int i = tid; i < NN_ * A_ / 2; i += 1024) ((uint*)s_ap)[i] = src[i];
  }
  if (tid < CD_) s_ce[tid] = ce[b * CD_ + tid];
  // attW columns for this thread's gate pair -> registers
  h2v aW[NN_];
  {
    const _Float16* base = attW_h + (size_t)b * NN_ * G4_ + 2 * tid;
#pragma unroll
    for (int n = 0; n < NN_; ++n) aW[n] = *(const h2v*)(base + (size_t)n * G4_);
  }
  float aw8[8];
#pragma unroll
  for (int i = 0; i < 8; ++i) aw8[i] = alpha_w[lane * 8 + i];
  const float ab  = alpha_b[0];
  const float ahb = (half == 0) ? att_hb[a9] : 0.f;
  __syncthreads();

  // h0 (threads 0..511): tanh(fcfeat . fcproj + b)
  float c_state = 0.f;
  if (tid < H_) {
    float acc = fcproj_b[tid];
    const h8v* xv = (const h8v*)s_gates;   // fcfeat lives here
    const h8v* wp = (const h8v*)fcproj_k;
    for (int k8 = 0; k8 < F_ / 8; ++k8)
      acc = dot8(xv[k8], wp[(size_t)k8 * 512 + tid], acc);
    s_h[tid] = (_Float16)tanh_f(acc);
  }
  // base for gate pair p = {2tid, 2tid+1}: b_ih + b_hh + ce . wcnt[p]
  float base0 = b_ih[2 * tid]     + b_hh[2 * tid];
  float base1 = b_ih[2 * tid + 1] + b_hh[2 * tid + 1];
  {
    const h8v* w0 = (const h8v*)(wcnt_h + (size_t)(2 * tid) * CD_);
    const h8v* w1 = (const h8v*)(wcnt_h + (size_t)(2 * tid + 1) * CD_);
#pragma unroll
    for (int k8 = 0; k8 < CD_ / 8; ++k8) {
      const h8v a = w0[k8], c = w1[k8];
#pragma unroll
      for (int i = 0; i < 8; ++i) {
        const float cv = s_ce[k8 * 8 + i];
        base0 += cv * (float)a[i];
        base1 += cv * (float)c[i];
      }
    }
  }
  __syncthreads();   // s_h ready; fcfeat area free for gates

  const h8v* atthw8 = (const h8v*)atthw_k;
  const h8v* whh8   = (const h8v*)whh_k;

  for (int t = 0; t < T_; ++t) {
    // ---- A: hp[a] = att_hb[a] + h . att_hw[a]  (split K across halves) ----
    {
      float acc = ahb;
      const h8v* hv = (const h8v*)s_h;
      const int k80 = half * 32;
#pragma unroll 8
      for (int k8 = k80; k8 < k80 + 32; ++k8)
        acc = dot8(hv[k8], atthw8[(size_t)k8 * 512 + a9], acc);
      s_hp2[half][a9] = acc;
    }
    __syncthreads();
    // ---- B: scores[n] = sum_a tanh(attproj[n][a] + hp[a]) * aw[a] ----
    {
      float hp8[8];
#pragma unroll
      for (int i = 0; i < 8; ++i) {
        const int a = lane * 8 + i;
        hp8[i] = s_hp2[0][a] + s_hp2[1][a];
      }
      const int Q = (wv == 0) ? 4 : 3;
      for (int q = 0; q < Q; ++q) {
        const int n = wv + 16 * q;
        const h8v apv = *(const h8v*)&s_ap[n * A_ + lane * 8];
        float s = 0.f;
#pragma unroll
        for (int i = 0; i < 8; ++i) {
          const float x = (float)apv[i] + hp8[i];
          const float e = __expf(2.f * fminf(fmaxf(x, -15.f), 15.f));
          s += __fdividef(e - 1.f, e + 1.f) * aw8[i];
        }
#pragma unroll
        for (int off = 32; off > 0; off >>= 1) s += __shfl_xor(s, off);
        if (lane == 0) s_sc[n] = s + ab;
      }
    }
    __syncthreads();
    // ---- C: softmax over 49 (wave 0) ----
    if (wv == 0) {
      float v = (lane < NN_) ? s_sc[lane] : -3.0e38f;
      float m = v;
#pragma unroll
      for (int off = 32; off > 0; off >>= 1) m = fmaxf(m, __shfl_xor(m, off));
      float e = (lane < NN_) ? __expf(v - m) : 0.f;
      float ssum = e;
#pragma unroll
      for (int off = 32; off > 0; off >>= 1) ssum += __shfl_xor(ssum, off);
      const float a = __fdividef(e, ssum);
      if (lane < NN_) {
        s_alpha[lane] = a;
        out_alpha[((size_t)b * T_ + t) * NN_ + lane] = a;
      }
    }
    __syncthreads();
    // ---- D: gate pair = base + we_proj + alpha@attW(reg) + h@whh(L2 stream) ----
    {
      const float2 wp = *(const float2*)(we_proj + ((size_t)b * T_ + t) * G4_ + 2 * tid);
      float acc0 = base0 + wp.x, acc1 = base1 + wp.y;
#pragma unroll
      for (int n = 0; n < NN_; ++n) {
        const float al = s_alpha[n];
        acc0 += al * (float)aW[n][0];
        acc1 += al * (float)aW[n][1];
      }
      const h8v* hv = (const h8v*)s_h;
#pragma unroll 4
      for (int k8 = 0; k8 < H_ / 8; ++k8) {
        const h8v x = hv[k8];
        acc0 = dot8(x, whh8[(size_t)k8 * G4_ + 2 * tid],     acc0);
        acc1 = dot8(x, whh8[(size_t)k8 * G4_ + 2 * tid + 1], acc1);
      }
      *(h2v*)&s_gates[2 * tid] = (h2v){ (_Float16)acc0, (_Float16)acc1 };
    }
    __syncthreads();
    // ---- E: LSTM cell (threads 0..511) ----
    if (tid < H_) {
      const int j = tid;
      const float gi = (float)s_gates[j];
      const float gf = (float)s_gates[512 + j];
      const float gg = (float)s_gates[1024 + j];
      const float go = (float)s_gates[1536 + j];
      const float si = sig_f(gi), sf = sig_f(gf), so = sig_f(go);
      c_state = sf * c_state + si * tanh_f(gg);
      const float hn = so * tanh_f(c_state);
      s_h[j] = (_Float16)hn;
      H_all_h[((size_t)b * T_ + t) * H_ + j] = (_Float16)hn;
    }
    __syncthreads();
  }
}

extern "C" void kernel_launch(void* const* d_in, const int* in_sizes, int n_in,
                              void* d_out, int out_size, void* d_ws, size_t ws_size,
                              hipStream_t stream) {
  const float* att_feats  = (const float*)d_in[0];
  const float* fc_feats   = (const float*)d_in[1];
  const int*   captions   = (const int*)  d_in[2];
  const float* count_vecs = (const float*)d_in[3];
  const float* embed_w    = (const float*)d_in[4];
  const float* cm_w1      = (const float*)d_in[5];
  const float* cm_b1      = (const float*)d_in[6];
  const float* cm_w2      = (const float*)d_in[7];
  const float* cm_b2      = (const float*)d_in[8];
  const float* att_hw     = (const float*)d_in[9];
  const float* att_hb     = (const float*)d_in[10];
  const float* att_fw     = (const float*)d_in[11];
  const float* att_fb     = (const float*)d_in[12];
  const float* alpha_w    = (const float*)d_in[13];
  const float* alpha_b    = (const float*)d_in[14];
  const float* fcproj_w   = (const float*)d_in[15];
  const float* fcproj_b   = (const float*)d_in[16];
  const float* w_ih       = (const float*)d_in[17];
  const float* b_ih       = (const float*)d_in[18];
  const float* w_hh       = (const float*)d_in[19];
  const float* b_hh       = (const float*)d_in[20];
  const float* fc_w       = (const float*)d_in[21];
  const float* fc_b       = (const float*)d_in[22];
  float* out = (float*)d_out;

  char* wsb = (char*)d_ws;
  size_t off = 0;
  auto nxt = [&](size_t bytes) { char* p = wsb + off; off += (bytes + 255) & ~(size_t)255; return p; };
  _Float16* att_th    = (_Float16*)nxt((size_t)B_*NN_*F_*2);
  _Float16* attW_h    = (_Float16*)nxt((size_t)B_*NN_*G4_*2);
  _Float16* attproj_h = (_Float16*)nxt((size_t)B_*NN_*A_*2);
  _Float16* we_h      = (_Float16*)nxt((size_t)B_*T_*E_*2);
  _Float16* H_all_h   = (_Float16*)nxt((size_t)B_*T_*H_*2);
  _Float16* w_ihF_h   = (_Float16*)nxt((size_t)G4_*F_*2);
  _Float16* w_ih0_h   = (_Float16*)nxt((size_t)G4_*E_*2);
  _Float16* wcnt_h    = (_Float16*)nxt((size_t)G4_*CD_*2);
  _Float16* fc_w_h    = (_Float16*)nxt((size_t)VP_*H_*2);
  _Float16* att_fw_h  = (_Float16*)nxt((size_t)A_*F_*2);
  _Float16* fcfeat_h  = (_Float16*)nxt((size_t)B_*F_*2);
  _Float16* whh_k     = (_Float16*)nxt((size_t)G4_*H_*2);
  _Float16* atthw_k   = (_Float16*)nxt((size_t)A_*H_*2);
  _Float16* fcproj_k  = (_Float16*)nxt((size_t)H_*F_*2);
  float*    we_proj   = (float*)nxt((size_t)B_*T_*G4_*4);
  float*    ce        = (float*)nxt((size_t)B_*CD_*4);
  if (off > ws_size) return;

  const size_t ALPHA_OFF = (size_t)B_ * T_ * V_;

  // ---- packs & small precompute ----
  transpose_att<<<dim3(F_/64, B_), 256, 0, stream>>>(att_feats, att_th);
  pack_h16<<<((size_t)B_*F_ + 255)/256, 256, 0, stream>>>(fc_feats, F_, 0, fcfeat_h, F_, B_, B_);
  pack_h16<<<((size_t)G4_*F_ + 255)/256, 256, 0, stream>>>(w_ih, E_+F_+CD_, E_, w_ihF_h, F_, G4_, G4_);
  pack_h16<<<((size_t)G4_*E_ + 255)/256, 256, 0, stream>>>(w_ih, E_+F_+CD_, 0, w_ih0_h, E_, G4_, G4_);
  pack_h16<<<((size_t)G4_*CD_ + 255)/256, 256, 0, stream>>>(w_ih, E_+F_+CD_, E_+F_, wcnt_h, CD_, G4_, G4_);
  pack_h16<<<((size_t)A_*F_ + 255)/256, 256, 0, stream>>>(att_fw, F_, 0, att_fw_h, F_, A_, A_);
  pack_h16<<<((size_t)VP_*H_ + 255)/256, 256, 0, stream>>>(fc_w, H_, 0, fc_w_h, H_, V_, VP_);
  pack_ki8<<<((size_t)G4_*H_ + 255)/256, 256, 0, stream>>>(w_hh, H_, 0, whh_k, G4_, H_);
  pack_ki8<<<((size_t)A_*H_ + 255)/256, 256, 0, stream>>>(att_hw, H_, 0, atthw_k, A_, H_);
  pack_ki8<<<((size_t)H_*F_ + 255)/256, 256, 0, stream>>>(fcproj_w, F_, 0, fcproj_k, H_, F_);
  count_embed_k<<<B_, 128, 0, stream>>>(count_vecs, cm_w1, cm_b1, cm_w2, cm_b2, ce);
  gather_we<<<B_ * T_, 128, 0, stream>>>(captions, embed_w, we_h);

  // ---- MFMA precompute GEMMs ----
  gemm_h16<1,1><<<dim3(A_/128, (B_*NN_)/128), 256, 0, stream>>>(
      att_th, F_, att_fw_h, F_, att_fb, attproj_h, A_, A_, F_);
  gemm_h16<1,0><<<dim3(G4_/128, (B_*NN_)/128), 256, 0, stream>>>(
      att_th, F_, w_ihF_h, F_, nullptr, attW_h, G4_, G4_, F_);
  gemm_h16<0,0><<<dim3(G4_/128, (B_*T_)/128), 256, 0, stream>>>(
      we_h, E_, w_ih0_h, E_, nullptr, we_proj, G4_, G4_, E_);

  // ---- persistent sequential loop ----
  seq_loop<<<B_, 1024, 0, stream>>>(fcfeat_h, fcproj_k, fcproj_b,
                                    wcnt_h, ce, b_ih, b_hh,
                                    atthw_k, att_hb,
                                    attproj_h, alpha_w, alpha_b,
                                    attW_h, we_proj, whh_k,
                                    H_all_h, out + ALPHA_OFF);

  // ---- logits = H_all @ fc_w^T + fc_b -> out (B*T, V) ----
  gemm_h16<0,1><<<dim3(VP_/128, (B_*T_)/128), 256, 0, stream>>>(
      H_all_h, H_, fc_w_h, H_, fc_b, out, V_, V_, H_);
}